// Round 6
// baseline (245.183 us; speedup 1.0000x reference)
//
#include <hip/hip_runtime.h>
#include <hip/hip_bf16.h>

#define CIN 64
#define COUT 64
#define BATCH 32
#define KTOT 576            // CIN*9
#define NPOS 1024
#define NKS 18              // 576 / 32 k-steps

// halo-padded transposed input: xT[i][34][34][b]
__device__ float g_xT[CIN * 34 * 34 * BATCH];

// Coalesced transpose repack (unchanged from R4 — passed, ~4-6 us)
__global__ __launch_bounds__(256) void repack_kernel(const float* __restrict__ x) {
    __shared__ float tile[32 * 33];
    const int i   = blockIdx.x;            // 0..63
    const int hh  = blockIdx.y;            // 0..33
    const int tid = threadIdx.x;

    float* dst = &g_xT[((i * 34 + hh) * 34) * BATCH];

    if (hh == 0 || hh == 33) {
        for (int idx = tid; idx < 34 * BATCH; idx += 256) dst[idx] = 0.f;
        return;
    }
    const int hs = hh - 1;
#pragma unroll
    for (int bb = 0; bb < 4; ++bb) {
        int b = bb * 8 + (tid >> 5);
        int w = tid & 31;
        tile[b * 33 + w] = x[(b << 16) + (i << 10) + (hs << 5) + w];
    }
    __syncthreads();
#pragma unroll
    for (int q = 0; q < 5; ++q) {
        int ww = q * 8 + (tid >> 5);
        if (ww < 34) {
            int b = tid & 31;
            float v = (ww == 0 || ww == 33) ? 0.f : tile[b * 33 + (ww - 1)];
            dst[ww * BATCH + b] = v;
        }
    }
}

typedef __attribute__((ext_vector_type(8))) short bf16x8;  // 8 bf16 (4 VGPRs)
typedef __attribute__((ext_vector_type(4))) float f32x4;   // MFMA C/D
typedef __attribute__((ext_vector_type(4))) float f32x4v;  // vector load type

union Frag { bf16x8 v; __hip_bfloat162 h[4]; };

__device__ __forceinline__ __hip_bfloat162 cvt2(float a, float b) {
    return __float22bfloat162_rn(make_float2(a, b));
}

// 2 waves/block, 1 block/position. Wave wv: o in [wv*32, wv*32+32) (2 A-tiles),
// both b-tiles (32 batch), full K=576. Zero LDS: W = direct nt-load in A-frag
// pattern; P = 16-dword gather from L2/L3-resident g_xT in B-frag pattern.
// 3-deep register pipeline, compiler-managed vmcnt. MFMA 16x16x32 bf16.
__global__ __launch_bounds__(128, 2) void local2d_kernel(
    const float* __restrict__ weight,
    const float* __restrict__ bias,
    float* __restrict__ out)
{
    const int wv = threadIdx.x >> 6;       // wave 0/1
    const int l  = threadIdx.x & 63;
    const int lm = l & 15;                 // frag row/col index
    const int a4 = l >> 4;                 // quad: k-group

    // row-granular XCD swizzle (R4): each XCD owns whole output rows
    int bid = blockIdx.x;
    int xcd = bid & 7;
    int t   = bid >> 3;
    int y   = ((t >> 5) << 3) | xcd;
    int xw  = t & 31;
    int p   = (y << 5) | xw;

    // W A-frag bases: lane holds W[o = obase + lm][k = ks*32 + a4*8 + j]
    const float* w0 = weight + ((long)p * COUT + (wv * 32 + lm)) * KTOT + a4 * 8;
    const float* w1 = w0 + 16 * KTOT;

    // P gather base: g_xT[((i*34 + y+kh)*34 + xw+kw)*32 + b], b0 = lm, b1 = lm+16
    const float* pbase = g_xT + ((y * 34) + xw) * BATCH + lm;

    f32x4 acc[2][2];
#pragma unroll
    for (int i0 = 0; i0 < 2; ++i0)
#pragma unroll
        for (int i1 = 0; i1 < 2; ++i1) acc[i0][i1] = (f32x4){0.f, 0.f, 0.f, 0.f};

    f32x4v wbuf[3][2][2];                  // [buf][o-tile][half]: fp32 W frags
    float  pbuf[3][2][8];                  // [buf][b-tile][j]

    auto issue = [&](int ks, int d) {
        // W: imm-offset nt loads (ks*128 B fits the 13-bit offset)
        wbuf[d][0][0] = __builtin_nontemporal_load((const f32x4v*)(w0 + ks * 32));
        wbuf[d][0][1] = __builtin_nontemporal_load((const f32x4v*)(w0 + ks * 32 + 4));
        wbuf[d][1][0] = __builtin_nontemporal_load((const f32x4v*)(w1 + ks * 32));
        wbuf[d][1][1] = __builtin_nontemporal_load((const f32x4v*)(w1 + ks * 32 + 4));
        // P: per j, decompose k -> (i,kh,kw), gather two b-tiles (+64 B)
#pragma unroll
        for (int j = 0; j < 8; ++j) {
            int k  = ks * 32 + a4 * 8 + j;
            int i  = (k * 7282) >> 16;     // k/9 for k<576
            int r  = k - 9 * i;
            int kh = (r * 11) >> 5;        // r/3 for r<9
            int kw = r - 3 * kh;
            const float* rp = pbase + (i * 1156 + kh * 34 + kw) * BATCH;
            pbuf[d][0][j] = rp[0];
            pbuf[d][1][j] = rp[16];
        }
    };

    auto consume = [&](int d) {
        Frag A[2], B[2];
#pragma unroll
        for (int t2 = 0; t2 < 2; ++t2) {
            A[t2].h[0] = cvt2(wbuf[d][t2][0].x, wbuf[d][t2][0].y);
            A[t2].h[1] = cvt2(wbuf[d][t2][0].z, wbuf[d][t2][0].w);
            A[t2].h[2] = cvt2(wbuf[d][t2][1].x, wbuf[d][t2][1].y);
            A[t2].h[3] = cvt2(wbuf[d][t2][1].z, wbuf[d][t2][1].w);
            B[t2].h[0] = cvt2(pbuf[d][t2][0], pbuf[d][t2][1]);
            B[t2].h[1] = cvt2(pbuf[d][t2][2], pbuf[d][t2][3]);
            B[t2].h[2] = cvt2(pbuf[d][t2][4], pbuf[d][t2][5]);
            B[t2].h[3] = cvt2(pbuf[d][t2][6], pbuf[d][t2][7]);
        }
#pragma unroll
        for (int t2 = 0; t2 < 2; ++t2)
#pragma unroll
            for (int bt = 0; bt < 2; ++bt)
                acc[t2][bt] = __builtin_amdgcn_mfma_f32_16x16x32_bf16(
                    A[t2].v, B[bt].v, acc[t2][bt], 0, 0, 0);
    };

    issue(0, 0);
    issue(1, 1);
#pragma unroll
    for (int ks = 0; ks < NKS; ++ks) {
        if (ks + 2 < NKS) issue(ks + 2, (ks + 2) % 3);
        consume(ks % 3);
    }

    // epilogue: C/D layout col=lane&15 (b), row=quad*4+reg (o)
#pragma unroll
    for (int t2 = 0; t2 < 2; ++t2) {
        int obase = wv * 32 + t2 * 16 + a4 * 4;
        float bv[4];
#pragma unroll
        for (int reg = 0; reg < 4; ++reg)
            bv[reg] = bias[((obase + reg) << 10) + p];
#pragma unroll
        for (int bt = 0; bt < 2; ++bt) {
            int b = bt * 16 + lm;
#pragma unroll
            for (int reg = 0; reg < 4; ++reg)
                out[(b << 16) + ((obase + reg) << 10) + p] =
                    acc[t2][bt][reg] + bv[reg];
        }
    }
}

extern "C" void kernel_launch(void* const* d_in, const int* in_sizes, int n_in,
                              void* d_out, int out_size, void* d_ws, size_t ws_size,
                              hipStream_t stream) {
    const float* x      = (const float*)d_in[0];
    const float* weight = (const float*)d_in[1];
    const float* bias   = (const float*)d_in[2];
    float* out          = (float*)d_out;

    hipLaunchKernelGGL(repack_kernel, dim3(CIN, 34), dim3(256), 0, stream, x);
    hipLaunchKernelGGL(local2d_kernel, dim3(NPOS), dim3(128), 0, stream,
                       weight, bias, out);
}